// Round 9
// baseline (444.783 us; speedup 1.0000x reference)
//
#include <hip/hip_runtime.h>
#include <hip/hip_fp16.h>

// ---------------------------------------------------------------------------
// GCN 3-layer forward on MI355X.
// R4: T stored fp16 (fabric-gather bytes halved).
// R5: GEMM -> v_mfma_f32_16x16x32_f16, W pre-packed frags, fp16 H between
//     layers (same A/B k-slot map so HW k-permutation cancels).
// R6: weightless CSR — T' = (H@W)*dinv[row] in GEMM epilogue; prop computes
//     dinv[d]*(sum T'[src] + T'[d]) + b; 4B src-only records.
// R8: global-atomic-free two-level counting sort (chist/cscan/cscatter/ffine).
// R9: prop accumulators f64 -> f32 (f64 was ~2.5x the hot-loop VALU work;
//     order effects at f32 ~1e-6, invisible at the 2e-3 absmax scale).
//     CH 8192->4096 (391 setup blocks, full CU coverage). wfrag x3 fused.
// ---------------------------------------------------------------------------

typedef _Float16 half8 __attribute__((ext_vector_type(8)));
typedef float floatx4 __attribute__((ext_vector_type(4)));

struct h4 { __half2 a, b; };  // 4 halves = 8 B

constexpr int CH = 4096;      // edges per chunk (chist/cscatter block)

// --- Pass 1: per-chunk coarse histogram (bucket = dst>>8, nbc<=512) --------
__global__ __launch_bounds__(256) void k_chist(const int* __restrict__ edst,
                                               int* __restrict__ histM, int E) {
    __shared__ int h[512];
    int tid = threadIdx.x;
    for (int i = tid; i < 512; i += 256) h[i] = 0;
    __syncthreads();
    int base = blockIdx.x * CH, end = min(E, base + CH);
    for (int e = base + tid; e < end; e += 256)
        atomicAdd(&h[edst[e] >> 8], 1);
    __syncthreads();
    int* row = histM + (size_t)blockIdx.x * 512;
    for (int i = tid; i < 512; i += 256) row[i] = h[i];
}

// --- Pass 2: one block; per-digit cross-chunk prefix + digit-total scan ----
__global__ __launch_bounds__(512) void k_cscan(const int* __restrict__ histM,
                                               int* __restrict__ boff,
                                               int* __restrict__ gbase, int nblk) {
    __shared__ int sh[512];
    int t = threadIdx.x;
    int tot = 0;
    for (int b = 0; b < nblk; b++) tot += histM[(size_t)b * 512 + t];
    int val = tot;
    sh[t] = val;
    __syncthreads();
    for (int off = 1; off < 512; off <<= 1) {
        int o = (t >= off) ? sh[t - off] : 0;
        __syncthreads();
        val += o;
        sh[t] = val;
        __syncthreads();
    }
    int gb = val - tot;          // exclusive digit base
    gbase[t] = gb;
    if (t == 511) gbase[512] = val;   // = E
    int run = gb;
    for (int b = 0; b < nblk; b++) {
        boff[(size_t)b * 512 + t] = run;
        run += histM[(size_t)b * 512 + t];
    }
}

// --- Pass 3: scatter into coarse-sorted stage; LDS cursors, no global atomics
// record: bits 24..31 = dst&255 (node within bucket), bits 0..23 = src
__global__ __launch_bounds__(256) void k_cscatter(const int* __restrict__ esrc,
                                                  const int* __restrict__ edst,
                                                  const int* __restrict__ boff,
                                                  unsigned* __restrict__ stage, int E) {
    __shared__ int cur[512];
    int tid = threadIdx.x;
    const int* row = boff + (size_t)blockIdx.x * 512;
    for (int i = tid; i < 512; i += 256) cur[i] = row[i];
    __syncthreads();
    int base = blockIdx.x * CH, end = min(E, base + CH);
    for (int e = base + tid; e < end; e += 256) {
        int s = esrc[e], d = edst[e];
        int pos = atomicAdd(&cur[d >> 8], 1);
        stage[pos] = ((unsigned)(d & 255) << 24) | (unsigned)s;
    }
}

// --- Pass 4: per-bucket fine sort; emits final epk (src), offs, dinv -------
__global__ __launch_bounds__(256) void k_ffine(const unsigned* __restrict__ stage,
                                               const int* __restrict__ gbase,
                                               unsigned* __restrict__ epk,
                                               int* __restrict__ offs,
                                               float* __restrict__ dinv,
                                               int n, int Etot) {
    int b = blockIdx.x, tid = threadIdx.x;
    int seg0 = gbase[b];
    int cnt = gbase[b + 1] - seg0;
    int node0 = b << 8, nn = min(256, n - node0);
    __shared__ int hist[256], sh[256], cur[256];
    hist[tid] = 0;
    __syncthreads();
    for (int i = tid; i < cnt; i += 256)
        atomicAdd(&hist[stage[seg0 + i] >> 24], 1);
    __syncthreads();
    int v = hist[tid];
    int val = v;
    sh[tid] = val;
    __syncthreads();
    for (int off = 1; off < 256; off <<= 1) {
        int o = (tid >= off) ? sh[tid - off] : 0;
        __syncthreads();
        val += o;
        sh[tid] = val;
        __syncthreads();
    }
    int excl = val - v;
    if (tid < nn) {
        offs[node0 + tid] = seg0 + excl;
        dinv[node0 + tid] = rsqrtf((float)(v + 1));   // +1 = self-loop
    }
    cur[tid] = seg0 + excl;
    __syncthreads();
    for (int i = tid; i < cnt; i += 256) {
        unsigned r = stage[seg0 + i];
        int pos = atomicAdd(&cur[r >> 24], 1);
        epk[pos] = r & 0x00FFFFFFu;
    }
    if (b == 0 && tid == 0) offs[n] = Etot;
}

// --- W fp32 -> fp16 MFMA fragment order, all 3 weights in one launch -------
//   slot(((ks*NT)+ct)*64 + lane)*8 + j  <-  W[ks*32 + (lane>>4)*8 + j][ct*16 + (lane&15)]
__global__ void k_wfrag3(const float* __restrict__ W1, _Float16* __restrict__ Wf1,
                         const float* __restrict__ W2, _Float16* __restrict__ Wf2,
                         const float* __restrict__ W3, _Float16* __restrict__ Wf3) {
    int blk = blockIdx.x;
    const float* W;
    _Float16* Wf;
    int F;
    if (blk < 8)      { W = W1; Wf = Wf1; F = 128; blk -= 0; }
    else if (blk < 16){ W = W2; Wf = Wf2; F = 128; blk -= 8; }
    else              { W = W3; Wf = Wf3; F = 64;  blk -= 16; }
    int NT = F / 16;
    int tid = blk * 256 + threadIdx.x;     // 0 .. 4*NT*64-1
    if (tid >= 4 * NT * 64) return;
    int lane = tid & 63;
    int ct = (tid >> 6) % NT;
    int ks = tid / (64 * NT);
    int k0 = ks * 32 + (lane >> 4) * 8;
    int c  = ct * 16 + (lane & 15);
#pragma unroll
    for (int j = 0; j < 8; j++)
        Wf[(size_t)tid * 8 + j] = (_Float16)W[(k0 + j) * F + c];
}

// --- T'[N,F] = (H[N,128] @ W[128,F]) * dinv[row], stored fp16 -------------
// 512 threads = 8 waves, 16 rows/wave. No LDS; B-frags L2-resident.
template <int F, bool IN32>
__global__ __launch_bounds__(512) void k_gemm_mfma(const void* __restrict__ Hv,
                                                   const _Float16* __restrict__ Wf,
                                                   const float* __restrict__ dinv,
                                                   _Float16* __restrict__ T, int n) {
    constexpr int NT = F / 16;                 // col tiles: 8 or 4
    int wave = threadIdx.x >> 6, lane = threadIdx.x & 63;
    int row0 = blockIdx.x * 128 + wave * 16;
    int arow = min(row0 + (lane & 15), n - 1); // clamp; stores guarded
    int k0 = (lane >> 4) * 8;
    const _Float16* Hh = (const _Float16*)Hv;
    const float*    Hf = (const float*)Hv;
    floatx4 acc[NT];
#pragma unroll
    for (int t = 0; t < NT; t++) acc[t] = floatx4{0.f, 0.f, 0.f, 0.f};
#pragma unroll
    for (int ks = 0; ks < 4; ks++) {
        half8 a;
        if constexpr (IN32) {
            const float* p = Hf + (size_t)arow * 128 + ks * 32 + k0;
            float4 f0 = *(const float4*)p;
            float4 f1 = *(const float4*)(p + 4);
            a[0] = (_Float16)f0.x; a[1] = (_Float16)f0.y;
            a[2] = (_Float16)f0.z; a[3] = (_Float16)f0.w;
            a[4] = (_Float16)f1.x; a[5] = (_Float16)f1.y;
            a[6] = (_Float16)f1.z; a[7] = (_Float16)f1.w;
        } else {
            a = *(const half8*)(Hh + (size_t)arow * 128 + ks * 32 + k0);
        }
#pragma unroll
        for (int t = 0; t < NT; t++) {
            half8 b = *(const half8*)(Wf + ((size_t)(ks * NT + t) * 64 + lane) * 8);
            acc[t] = __builtin_amdgcn_mfma_f32_16x16x32_f16(a, b, acc[t], 0, 0, 0);
        }
    }
    // C/D layout (m89-verified): col = lane&15, row = (lane>>4)*4 + reg
    int rbase = row0 + (lane >> 4) * 4;
    int cl = lane & 15;
#pragma unroll
    for (int r = 0; r < 4; r++) {
        int rr = rbase + r;
        if (rr < n) {
            float sc = dinv[rr];
#pragma unroll
            for (int t = 0; t < NT; t++)
                T[(size_t)rr * F + t * 16 + cl] = (_Float16)(acc[t][r] * sc);
        }
    }
}

// --- prop: out[g] = dinv[g]*(sum_{src in seg} T'[src] + T'[g]) + b --------
// One GRP-lane group per node; 4B src records (16/line, L1 broadcast);
// 4x unrolled gathers; f32 accumulators (order noise ~1e-6 << 2e-3 scale).
template <int F, bool RELU, typename OT>
__global__ __launch_bounds__(256) void k_prop(const __half* __restrict__ T,
                                              const int* __restrict__ offs,
                                              const unsigned* __restrict__ epk,
                                              const float* __restrict__ dinv,
                                              const float* __restrict__ bias,
                                              OT* __restrict__ Out, int n) {
    constexpr int GRP = F / 4;              // 32 (F=128) or 16 (F=64)
    int g  = (int)((blockIdx.x * blockDim.x + threadIdx.x) / GRP);  // node id
    int fl = threadIdx.x % GRP;             // feature lane
    if (g >= n) return;
    int j = offs[g], end = offs[g + 1];
    float a0 = 0.f, a1 = 0.f, a2 = 0.f, a3 = 0.f;
    for (; j + 4 <= end; j += 4) {
        unsigned s0 = epk[j + 0], s1 = epk[j + 1];
        unsigned s2 = epk[j + 2], s3 = epk[j + 3];
        h4 v0 = *(const h4*)&T[(size_t)s0 * F + fl * 4];
        h4 v1 = *(const h4*)&T[(size_t)s1 * F + fl * 4];
        h4 v2 = *(const h4*)&T[(size_t)s2 * F + fl * 4];
        h4 v3 = *(const h4*)&T[(size_t)s3 * F + fl * 4];
        float2 f0a = __half22float2(v0.a), f0b = __half22float2(v0.b);
        float2 f1a = __half22float2(v1.a), f1b = __half22float2(v1.b);
        float2 f2a = __half22float2(v2.a), f2b = __half22float2(v2.b);
        float2 f3a = __half22float2(v3.a), f3b = __half22float2(v3.b);
        a0 += f0a.x + f1a.x + f2a.x + f3a.x;
        a1 += f0a.y + f1a.y + f2a.y + f3a.y;
        a2 += f0b.x + f1b.x + f2b.x + f3b.x;
        a3 += f0b.y + f1b.y + f2b.y + f3b.y;
    }
    for (; j < end; j++) {
        unsigned s = epk[j];
        h4 v = *(const h4*)&T[(size_t)s * F + fl * 4];
        float2 fa = __half22float2(v.a), fb = __half22float2(v.b);
        a0 += fa.x;
        a1 += fa.y;
        a2 += fb.x;
        a3 += fb.y;
    }
    // self-loop term
    h4 vs = *(const h4*)&T[(size_t)g * F + fl * 4];
    float2 sa = __half22float2(vs.a), sb = __half22float2(vs.b);
    a0 += sa.x; a1 += sa.y;
    a2 += sb.x; a3 += sb.y;
    float dv = dinv[g];
    float4 b = *(const float4*)&bias[fl * 4];
    float r0 = a0 * dv + b.x;
    float r1 = a1 * dv + b.y;
    float r2 = a2 * dv + b.z;
    float r3 = a3 * dv + b.w;
    if (RELU) {
        r0 = fmaxf(r0, 0.f); r1 = fmaxf(r1, 0.f);
        r2 = fmaxf(r2, 0.f); r3 = fmaxf(r3, 0.f);
    }
    if constexpr (sizeof(OT) == 2) {
        h4 pk;
        pk.a = __floats2half2_rn(r0, r1);
        pk.b = __floats2half2_rn(r2, r3);
        *(h4*)&Out[(size_t)g * F + fl * 4] = pk;
    } else {
        *(float4*)&Out[(size_t)g * F + fl * 4] = float4{r0, r1, r2, r3};
    }
}

extern "C" void kernel_launch(void* const* d_in, const int* in_sizes, int n_in,
                              void* d_out, int out_size, void* d_ws, size_t ws_size,
                              hipStream_t stream) {
    const float* x  = (const float*)d_in[0];
    const int*   ei = (const int*)d_in[1];
    const float* W1 = (const float*)d_in[2];
    const float* b1 = (const float*)d_in[3];
    const float* W2 = (const float*)d_in[4];
    const float* b2 = (const float*)d_in[5];
    const float* W3 = (const float*)d_in[6];
    const float* b3 = (const float*)d_in[7];
    float* out = (float*)d_out;

    const int HID = in_sizes[3];            // 128
    const int IN  = in_sizes[2] / HID;      // 128
    const int N   = in_sizes[0] / IN;       // 100000
    const int E   = in_sizes[1] / 2;        // 1600000
    const int NBC  = (N + 255) >> 8;        // coarse buckets (391, <=512)
    const int NBLK = (E + CH - 1) / CH;     // chunks (391)

    const int* esrc = ei;
    const int* edst = ei + E;

    // workspace carve-up (256B aligned)
    char* p = (char*)d_ws;
    auto alloc = [&](size_t bytes) {
        void* r = (void*)p;
        p += (bytes + 255) & ~(size_t)255;
        return r;
    };
    float*    dinv  = (float*)alloc((size_t)N * 4);
    int*      offs  = (int*)alloc((size_t)(N + 1) * 4);
    int*      histM = (int*)alloc((size_t)NBLK * 512 * 4);
    int*      boff  = (int*)alloc((size_t)NBLK * 512 * 4);
    int*      gbase = (int*)alloc((size_t)513 * 4);
    unsigned* stage = (unsigned*)alloc((size_t)E * 4);
    unsigned* epk   = (unsigned*)alloc((size_t)E * 4);
    _Float16* t0    = (_Float16*)alloc((size_t)N * 128 * 2);
    _Float16* h0    = (_Float16*)alloc((size_t)N * 128 * 2);
    _Float16* wf1   = (_Float16*)alloc((size_t)128 * 128 * 2);
    _Float16* wf2   = (_Float16*)alloc((size_t)128 * 128 * 2);
    _Float16* wf3   = (_Float16*)alloc((size_t)128 * 64 * 2);
    (void)ws_size; (void)n_in; (void)out_size;

    const int B = 256;
    // --- CSR build: global-atomic-free two-level counting sort ---
    k_chist<<<NBLK, B, 0, stream>>>(edst, histM, E);
    k_cscan<<<1, 512, 0, stream>>>(histM, boff, gbase, NBLK);
    k_cscatter<<<NBLK, B, 0, stream>>>(esrc, edst, boff, stage, E);
    k_ffine<<<NBC, B, 0, stream>>>(stage, gbase, epk, offs, dinv, N, E);
    // --- W -> fp16 fragment packs (one fused launch) ---
    k_wfrag3<<<20, B, 0, stream>>>(W1, wf1, W2, wf2, W3, wf3);

    const int gb    = (N + 127) / 128;                     // gemm row-blocks
    const int pb128 = (int)(((size_t)N * 32 + B - 1) / B); // prop F=128 blocks
    const int pb64  = (int)(((size_t)N * 16 + B - 1) / B); // prop F=64 blocks
    // --- layer 1 (A from fp32 x, converted in-kernel) ---
    k_gemm_mfma<128, true><<<gb, 512, 0, stream>>>(x, wf1, dinv, t0, N);
    k_prop<128, true, __half><<<pb128, B, 0, stream>>>((const __half*)t0, offs, epk, dinv, b1, (__half*)h0, N);
    // --- layer 2 ---
    k_gemm_mfma<128, false><<<gb, 512, 0, stream>>>(h0, wf2, dinv, t0, N);
    k_prop<128, true, __half><<<pb128, B, 0, stream>>>((const __half*)t0, offs, epk, dinv, b2, (__half*)h0, N);
    // --- layer 3 (OUT=64, no relu, fp32 into d_out) ---
    k_gemm_mfma<64, false><<<gb, 512, 0, stream>>>(h0, wf3, dinv, t0, N);
    k_prop<64, false, float><<<pb64, B, 0, stream>>>((const __half*)t0, offs, epk, dinv, b3, out, N);
}

// Round 10
// 361.123 us; speedup vs baseline: 1.2317x; 1.2317x over previous
//
#include <hip/hip_runtime.h>
#include <hip/hip_fp16.h>

// ---------------------------------------------------------------------------
// GCN 3-layer forward on MI355X.
// R4: T stored fp16 (fabric-gather bytes halved).
// R5: GEMM -> v_mfma_f32_16x16x32_f16, W pre-packed frags, fp16 H between
//     layers (same A/B k-slot map so HW k-permutation cancels).
// R6: weightless CSR — T' = (H@W)*dinv[row] in GEMM epilogue; prop computes
//     dinv[d]*(sum T'[src] + T'[d]) + b; 4B src-only records.
// R8: global-atomic-free two-level counting sort (chist/cscatter/ffine).
// R9: prop accumulators f64 -> f32; CH=4096; wfrag x3 fused.
// R10: cross-chunk scan parallelized — the single-block k_cscan (2 serial
//      391-iter loops, 99us @ 0.09% occupancy) becomes k_dscan (512 blocks,
//      one per digit, in-LDS scan over chunks) + k_gscan (1 block over 512
//      digit totals). cscatter cursors = gbase[d] + boffL[blk][d].
// ---------------------------------------------------------------------------

typedef _Float16 half8 __attribute__((ext_vector_type(8)));
typedef float floatx4 __attribute__((ext_vector_type(4)));

struct h4 { __half2 a, b; };  // 4 halves = 8 B

constexpr int CH = 4096;      // edges per chunk (chist/cscatter block)

// --- Pass 1: per-chunk coarse histogram (bucket = dst>>8, nbc<=512) --------
__global__ __launch_bounds__(256) void k_chist(const int* __restrict__ edst,
                                               int* __restrict__ histM, int E) {
    __shared__ int h[512];
    int tid = threadIdx.x;
    for (int i = tid; i < 512; i += 256) h[i] = 0;
    __syncthreads();
    int base = blockIdx.x * CH, end = min(E, base + CH);
    for (int e = base + tid; e < end; e += 256)
        atomicAdd(&h[edst[e] >> 8], 1);
    __syncthreads();
    int* row = histM + (size_t)blockIdx.x * 512;
    for (int i = tid; i < 512; i += 256) row[i] = h[i];
}

// --- Pass 2a: per-digit prefix over chunks. One block per digit (512 blocks).
// nblk <= 512 assumed (E=1.6M, CH=4096 -> 391).
__global__ __launch_bounds__(256) void k_dscan(const int* __restrict__ histM,
                                               int* __restrict__ boffL,
                                               int* __restrict__ dtot, int nblk) {
    int d = blockIdx.x;          // digit
    int t = threadIdx.x;
    __shared__ int sh[256];
    int i0 = 2 * t, i1 = 2 * t + 1;
    int v0 = (i0 < nblk) ? histM[(size_t)i0 * 512 + d] : 0;
    int v1 = (i1 < nblk) ? histM[(size_t)i1 * 512 + d] : 0;
    int tsum = v0 + v1;
    int val = tsum;
    sh[t] = val;
    __syncthreads();
    for (int off = 1; off < 256; off <<= 1) {
        int o = (t >= off) ? sh[t - off] : 0;
        __syncthreads();
        val += o;
        sh[t] = val;
        __syncthreads();
    }
    int excl = val - tsum;       // exclusive over chunk-pairs
    if (i0 < nblk) boffL[(size_t)i0 * 512 + d] = excl;
    if (i1 < nblk) boffL[(size_t)i1 * 512 + d] = excl + v0;
    if (t == 255) dtot[d] = val; // digit total
}

// --- Pass 2b: one block; exclusive scan of 512 digit totals -> gbase -------
__global__ __launch_bounds__(512) void k_gscan(const int* __restrict__ dtot,
                                               int* __restrict__ gbase) {
    __shared__ int sh[512];
    int t = threadIdx.x;
    int v = dtot[t];
    int val = v;
    sh[t] = val;
    __syncthreads();
    for (int off = 1; off < 512; off <<= 1) {
        int o = (t >= off) ? sh[t - off] : 0;
        __syncthreads();
        val += o;
        sh[t] = val;
        __syncthreads();
    }
    gbase[t] = val - v;               // exclusive
    if (t == 511) gbase[512] = val;   // = E
}

// --- Pass 3: scatter into coarse-sorted stage; LDS cursors, no global atomics
// record: bits 24..31 = dst&255 (node within bucket), bits 0..23 = src
__global__ __launch_bounds__(256) void k_cscatter(const int* __restrict__ esrc,
                                                  const int* __restrict__ edst,
                                                  const int* __restrict__ boffL,
                                                  const int* __restrict__ gbase,
                                                  unsigned* __restrict__ stage, int E) {
    __shared__ int cur[512];
    int tid = threadIdx.x;
    const int* row = boffL + (size_t)blockIdx.x * 512;
    for (int i = tid; i < 512; i += 256) cur[i] = gbase[i] + row[i];
    __syncthreads();
    int base = blockIdx.x * CH, end = min(E, base + CH);
    for (int e = base + tid; e < end; e += 256) {
        int s = esrc[e], d = edst[e];
        int pos = atomicAdd(&cur[d >> 8], 1);
        stage[pos] = ((unsigned)(d & 255) << 24) | (unsigned)s;
    }
}

// --- Pass 4: per-bucket fine sort; emits final epk (src), offs, dinv -------
__global__ __launch_bounds__(256) void k_ffine(const unsigned* __restrict__ stage,
                                               const int* __restrict__ gbase,
                                               unsigned* __restrict__ epk,
                                               int* __restrict__ offs,
                                               float* __restrict__ dinv,
                                               int n, int Etot) {
    int b = blockIdx.x, tid = threadIdx.x;
    int seg0 = gbase[b];
    int cnt = gbase[b + 1] - seg0;
    int node0 = b << 8, nn = min(256, n - node0);
    __shared__ int hist[256], sh[256], cur[256];
    hist[tid] = 0;
    __syncthreads();
    for (int i = tid; i < cnt; i += 256)
        atomicAdd(&hist[stage[seg0 + i] >> 24], 1);
    __syncthreads();
    int v = hist[tid];
    int val = v;
    sh[tid] = val;
    __syncthreads();
    for (int off = 1; off < 256; off <<= 1) {
        int o = (tid >= off) ? sh[tid - off] : 0;
        __syncthreads();
        val += o;
        sh[tid] = val;
        __syncthreads();
    }
    int excl = val - v;
    if (tid < nn) {
        offs[node0 + tid] = seg0 + excl;
        dinv[node0 + tid] = rsqrtf((float)(v + 1));   // +1 = self-loop
    }
    cur[tid] = seg0 + excl;
    __syncthreads();
    for (int i = tid; i < cnt; i += 256) {
        unsigned r = stage[seg0 + i];
        int pos = atomicAdd(&cur[r >> 24], 1);
        epk[pos] = r & 0x00FFFFFFu;
    }
    if (b == 0 && tid == 0) offs[n] = Etot;
}

// --- W fp32 -> fp16 MFMA fragment order, all 3 weights in one launch -------
//   slot(((ks*NT)+ct)*64 + lane)*8 + j  <-  W[ks*32 + (lane>>4)*8 + j][ct*16 + (lane&15)]
__global__ void k_wfrag3(const float* __restrict__ W1, _Float16* __restrict__ Wf1,
                         const float* __restrict__ W2, _Float16* __restrict__ Wf2,
                         const float* __restrict__ W3, _Float16* __restrict__ Wf3) {
    int blk = blockIdx.x;
    const float* W;
    _Float16* Wf;
    int F;
    if (blk < 8)      { W = W1; Wf = Wf1; F = 128; blk -= 0; }
    else if (blk < 16){ W = W2; Wf = Wf2; F = 128; blk -= 8; }
    else              { W = W3; Wf = Wf3; F = 64;  blk -= 16; }
    int NT = F / 16;
    int tid = blk * 256 + threadIdx.x;     // 0 .. 4*NT*64-1
    if (tid >= 4 * NT * 64) return;
    int lane = tid & 63;
    int ct = (tid >> 6) % NT;
    int ks = tid / (64 * NT);
    int k0 = ks * 32 + (lane >> 4) * 8;
    int c  = ct * 16 + (lane & 15);
#pragma unroll
    for (int j = 0; j < 8; j++)
        Wf[(size_t)tid * 8 + j] = (_Float16)W[(k0 + j) * F + c];
}

// --- T'[N,F] = (H[N,128] @ W[128,F]) * dinv[row], stored fp16 -------------
// 512 threads = 8 waves, 16 rows/wave. No LDS; B-frags L2-resident.
template <int F, bool IN32>
__global__ __launch_bounds__(512) void k_gemm_mfma(const void* __restrict__ Hv,
                                                   const _Float16* __restrict__ Wf,
                                                   const float* __restrict__ dinv,
                                                   _Float16* __restrict__ T, int n) {
    constexpr int NT = F / 16;                 // col tiles: 8 or 4
    int wave = threadIdx.x >> 6, lane = threadIdx.x & 63;
    int row0 = blockIdx.x * 128 + wave * 16;
    int arow = min(row0 + (lane & 15), n - 1); // clamp; stores guarded
    int k0 = (lane >> 4) * 8;
    const _Float16* Hh = (const _Float16*)Hv;
    const float*    Hf = (const float*)Hv;
    floatx4 acc[NT];
#pragma unroll
    for (int t = 0; t < NT; t++) acc[t] = floatx4{0.f, 0.f, 0.f, 0.f};
#pragma unroll
    for (int ks = 0; ks < 4; ks++) {
        half8 a;
        if constexpr (IN32) {
            const float* p = Hf + (size_t)arow * 128 + ks * 32 + k0;
            float4 f0 = *(const float4*)p;
            float4 f1 = *(const float4*)(p + 4);
            a[0] = (_Float16)f0.x; a[1] = (_Float16)f0.y;
            a[2] = (_Float16)f0.z; a[3] = (_Float16)f0.w;
            a[4] = (_Float16)f1.x; a[5] = (_Float16)f1.y;
            a[6] = (_Float16)f1.z; a[7] = (_Float16)f1.w;
        } else {
            a = *(const half8*)(Hh + (size_t)arow * 128 + ks * 32 + k0);
        }
#pragma unroll
        for (int t = 0; t < NT; t++) {
            half8 b = *(const half8*)(Wf + ((size_t)(ks * NT + t) * 64 + lane) * 8);
            acc[t] = __builtin_amdgcn_mfma_f32_16x16x32_f16(a, b, acc[t], 0, 0, 0);
        }
    }
    // C/D layout (m89-verified): col = lane&15, row = (lane>>4)*4 + reg
    int rbase = row0 + (lane >> 4) * 4;
    int cl = lane & 15;
#pragma unroll
    for (int r = 0; r < 4; r++) {
        int rr = rbase + r;
        if (rr < n) {
            float sc = dinv[rr];
#pragma unroll
            for (int t = 0; t < NT; t++)
                T[(size_t)rr * F + t * 16 + cl] = (_Float16)(acc[t][r] * sc);
        }
    }
}

// --- prop: out[g] = dinv[g]*(sum_{src in seg} T'[src] + T'[g]) + b --------
// One GRP-lane group per node; 4B src records (16/line, L1 broadcast);
// 4x unrolled gathers; f32 accumulators (order noise ~1e-6 << 2e-3 scale).
template <int F, bool RELU, typename OT>
__global__ __launch_bounds__(256) void k_prop(const __half* __restrict__ T,
                                              const int* __restrict__ offs,
                                              const unsigned* __restrict__ epk,
                                              const float* __restrict__ dinv,
                                              const float* __restrict__ bias,
                                              OT* __restrict__ Out, int n) {
    constexpr int GRP = F / 4;              // 32 (F=128) or 16 (F=64)
    int g  = (int)((blockIdx.x * blockDim.x + threadIdx.x) / GRP);  // node id
    int fl = threadIdx.x % GRP;             // feature lane
    if (g >= n) return;
    int j = offs[g], end = offs[g + 1];
    float a0 = 0.f, a1 = 0.f, a2 = 0.f, a3 = 0.f;
    for (; j + 4 <= end; j += 4) {
        unsigned s0 = epk[j + 0], s1 = epk[j + 1];
        unsigned s2 = epk[j + 2], s3 = epk[j + 3];
        h4 v0 = *(const h4*)&T[(size_t)s0 * F + fl * 4];
        h4 v1 = *(const h4*)&T[(size_t)s1 * F + fl * 4];
        h4 v2 = *(const h4*)&T[(size_t)s2 * F + fl * 4];
        h4 v3 = *(const h4*)&T[(size_t)s3 * F + fl * 4];
        float2 f0a = __half22float2(v0.a), f0b = __half22float2(v0.b);
        float2 f1a = __half22float2(v1.a), f1b = __half22float2(v1.b);
        float2 f2a = __half22float2(v2.a), f2b = __half22float2(v2.b);
        float2 f3a = __half22float2(v3.a), f3b = __half22float2(v3.b);
        a0 += f0a.x + f1a.x + f2a.x + f3a.x;
        a1 += f0a.y + f1a.y + f2a.y + f3a.y;
        a2 += f0b.x + f1b.x + f2b.x + f3b.x;
        a3 += f0b.y + f1b.y + f2b.y + f3b.y;
    }
    for (; j < end; j++) {
        unsigned s = epk[j];
        h4 v = *(const h4*)&T[(size_t)s * F + fl * 4];
        float2 fa = __half22float2(v.a), fb = __half22float2(v.b);
        a0 += fa.x;
        a1 += fa.y;
        a2 += fb.x;
        a3 += fb.y;
    }
    // self-loop term
    h4 vs = *(const h4*)&T[(size_t)g * F + fl * 4];
    float2 sa = __half22float2(vs.a), sb = __half22float2(vs.b);
    a0 += sa.x; a1 += sa.y;
    a2 += sb.x; a3 += sb.y;
    float dv = dinv[g];
    float4 b = *(const float4*)&bias[fl * 4];
    float r0 = a0 * dv + b.x;
    float r1 = a1 * dv + b.y;
    float r2 = a2 * dv + b.z;
    float r3 = a3 * dv + b.w;
    if (RELU) {
        r0 = fmaxf(r0, 0.f); r1 = fmaxf(r1, 0.f);
        r2 = fmaxf(r2, 0.f); r3 = fmaxf(r3, 0.f);
    }
    if constexpr (sizeof(OT) == 2) {
        h4 pk;
        pk.a = __floats2half2_rn(r0, r1);
        pk.b = __floats2half2_rn(r2, r3);
        *(h4*)&Out[(size_t)g * F + fl * 4] = pk;
    } else {
        *(float4*)&Out[(size_t)g * F + fl * 4] = float4{r0, r1, r2, r3};
    }
}

extern "C" void kernel_launch(void* const* d_in, const int* in_sizes, int n_in,
                              void* d_out, int out_size, void* d_ws, size_t ws_size,
                              hipStream_t stream) {
    const float* x  = (const float*)d_in[0];
    const int*   ei = (const int*)d_in[1];
    const float* W1 = (const float*)d_in[2];
    const float* b1 = (const float*)d_in[3];
    const float* W2 = (const float*)d_in[4];
    const float* b2 = (const float*)d_in[5];
    const float* W3 = (const float*)d_in[6];
    const float* b3 = (const float*)d_in[7];
    float* out = (float*)d_out;

    const int HID = in_sizes[3];            // 128
    const int IN  = in_sizes[2] / HID;      // 128
    const int N   = in_sizes[0] / IN;       // 100000
    const int E   = in_sizes[1] / 2;        // 1600000
    const int NBC  = (N + 255) >> 8;        // coarse buckets (391, <=512)
    const int NBLK = (E + CH - 1) / CH;     // chunks (391, <=512)

    const int* esrc = ei;
    const int* edst = ei + E;

    // workspace carve-up (256B aligned)
    char* p = (char*)d_ws;
    auto alloc = [&](size_t bytes) {
        void* r = (void*)p;
        p += (bytes + 255) & ~(size_t)255;
        return r;
    };
    float*    dinv  = (float*)alloc((size_t)N * 4);
    int*      offs  = (int*)alloc((size_t)(N + 1) * 4);
    int*      histM = (int*)alloc((size_t)NBLK * 512 * 4);
    int*      boffL = (int*)alloc((size_t)NBLK * 512 * 4);
    int*      dtot  = (int*)alloc((size_t)512 * 4);
    int*      gbase = (int*)alloc((size_t)513 * 4);
    unsigned* stage = (unsigned*)alloc((size_t)E * 4);
    unsigned* epk   = (unsigned*)alloc((size_t)E * 4);
    _Float16* t0    = (_Float16*)alloc((size_t)N * 128 * 2);
    _Float16* h0    = (_Float16*)alloc((size_t)N * 128 * 2);
    _Float16* wf1   = (_Float16*)alloc((size_t)128 * 128 * 2);
    _Float16* wf2   = (_Float16*)alloc((size_t)128 * 128 * 2);
    _Float16* wf3   = (_Float16*)alloc((size_t)128 * 64 * 2);
    (void)ws_size; (void)n_in; (void)out_size;

    const int B = 256;
    // --- CSR build: global-atomic-free two-level counting sort ---
    k_chist<<<NBLK, B, 0, stream>>>(edst, histM, E);
    k_dscan<<<512, B, 0, stream>>>(histM, boffL, dtot, NBLK);
    k_gscan<<<1, 512, 0, stream>>>(dtot, gbase);
    k_cscatter<<<NBLK, B, 0, stream>>>(esrc, edst, boffL, gbase, stage, E);
    k_ffine<<<NBC, B, 0, stream>>>(stage, gbase, epk, offs, dinv, N, E);
    // --- W -> fp16 fragment packs (one fused launch) ---
    k_wfrag3<<<20, B, 0, stream>>>(W1, wf1, W2, wf2, W3, wf3);

    const int gb    = (N + 127) / 128;                     // gemm row-blocks
    const int pb128 = (int)(((size_t)N * 32 + B - 1) / B); // prop F=128 blocks
    const int pb64  = (int)(((size_t)N * 16 + B - 1) / B); // prop F=64 blocks
    // --- layer 1 (A from fp32 x, converted in-kernel) ---
    k_gemm_mfma<128, true><<<gb, 512, 0, stream>>>(x, wf1, dinv, t0, N);
    k_prop<128, true, __half><<<pb128, B, 0, stream>>>((const __half*)t0, offs, epk, dinv, b1, (__half*)h0, N);
    // --- layer 2 ---
    k_gemm_mfma<128, false><<<gb, 512, 0, stream>>>(h0, wf2, dinv, t0, N);
    k_prop<128, true, __half><<<pb128, B, 0, stream>>>((const __half*)t0, offs, epk, dinv, b2, (__half*)h0, N);
    // --- layer 3 (OUT=64, no relu, fp32 into d_out) ---
    k_gemm_mfma<64, false><<<gb, 512, 0, stream>>>(h0, wf3, dinv, t0, N);
    k_prop<64, false, float><<<pb64, B, 0, stream>>>((const __half*)t0, offs, epk, dinv, b3, out, N);
}